// Round 14
// baseline (414.620 us; speedup 1.0000x reference)
//
#include <hip/hip_runtime.h>

#define BB 4
#define NN 10000
#define EE 320000
#define HH 128
#define HALFN 5000
#define NK2 (2 * NN)       // CSR keys per graph: (srcHalf, col)
#define RS (2 * NN + 1)
#define NHB 64             // histogram blocks per graph
#define EPB (EE / NHB)     // 5000 edges per histogram block

typedef int i32x2 __attribute__((ext_vector_type(2)));
typedef float f32x4 __attribute__((ext_vector_type(4)));

// ---------------------------------------------------------------------------
// 1) hist: per-block LDS histogram (counts + float weight sums) over keys,
//    two half-passes. Emits per-edge local rank (ushort), per-block count
//    histogram hb[blk][key] and weight-sum partials wsp[blk][key].
// ---------------------------------------------------------------------------
__global__ __launch_bounds__(256) void hist_kernel(
    const int* __restrict__ edges, const float* __restrict__ attr,
    unsigned short* __restrict__ hb, float* __restrict__ wsp,
    unsigned short* __restrict__ lrank) {
  __shared__ int lh[NN];     // 40 KB
  __shared__ float lw[NN];   // 40 KB
  int b = blockIdx.y, blk = blockIdx.x, t = threadIdx.x;
  const int* rows = edges + (size_t)b * 2 * EE;
  const int* cols = rows + EE;
  const float* wa = attr + (size_t)b * EE;
#pragma unroll
  for (int half = 0; half < 2; ++half) {
    for (int i = t; i < NN; i += 256) { lh[i] = 0; lw[i] = 0.f; }
    __syncthreads();
    for (int i = t; i < EPB; i += 256) {
      int e = blk * EPB + i;
      int row = rows[e];
      if ((row >= HALFN) == (half != 0)) {
        int col = cols[e];
        int lr = atomicAdd(&lh[col], 1);
        atomicAdd(&lw[col], wa[e]);
        lrank[(size_t)b * EE + e] = (unsigned short)lr;
      }
    }
    __syncthreads();
    unsigned short* hbrow = hb + ((size_t)(b * NHB + blk)) * NK2 + half * NN;
    float* wsrow = wsp + ((size_t)(b * NHB + blk)) * NK2 + half * NN;
    for (int i = t; i < NN; i += 256) {
      hbrow[i] = (unsigned short)lh[i];
      wsrow[i] = lw[i];
    }
    __syncthreads();
  }
}

// ---------------------------------------------------------------------------
// 2) colscan: per key, exclusive prefix of counts over the 64 blocks
//    (in place) + total weight sum -> cnt[key], wtot[key]
// ---------------------------------------------------------------------------
__global__ __launch_bounds__(256) void colscan_kernel(
    unsigned short* __restrict__ hb, const float* __restrict__ wsp,
    int* __restrict__ cnt, float* __restrict__ wtot) {
  int b = blockIdx.y;
  int k = blockIdx.x * 256 + threadIdx.x;
  if (k >= NK2) return;
  int acc = 0;
  float f = 0.f;
  for (int j = 0; j < NHB; ++j) {
    size_t idx = ((size_t)(b * NHB + j)) * NK2 + k;
    int v = hb[idx];
    hb[idx] = (unsigned short)acc;
    acc += v;
    f += wsp[idx];
  }
  cnt[b * NK2 + k] = acc;
  wtot[b * NK2 + k] = f;
}

// ---------------------------------------------------------------------------
// 3) scan: exclusive scan of cnt -> rowstart; also dinv = rsqrt(deg) from wtot
// ---------------------------------------------------------------------------
__global__ __launch_bounds__(256) void scan_kernel(
    const int* __restrict__ cnt, const float* __restrict__ wtot,
    int* __restrict__ rowstart, float* __restrict__ dinv) {
  int b = blockIdx.x, t = threadIdx.x;
  __shared__ int s[256];
  int running = 0;
  for (int base = 0; base < NK2; base += 2048) {
    int v[8];
    int i0 = base + t * 8;
    int tsum = 0;
#pragma unroll
    for (int j = 0; j < 8; ++j) {
      v[j] = (i0 + j < NK2) ? cnt[b * NK2 + i0 + j] : 0;
      tsum += v[j];
    }
    s[t] = tsum;
    __syncthreads();
    for (int o = 1; o < 256; o <<= 1) {
      int add = (t >= o) ? s[t - o] : 0;
      __syncthreads();
      s[t] += add;
      __syncthreads();
    }
    int ex = running + s[t] - tsum;
#pragma unroll
    for (int j = 0; j < 8; ++j) {
      if (i0 + j < NK2) rowstart[b * RS + i0 + j] = ex;
      ex += v[j];
    }
    int tot = s[255];
    __syncthreads();
    running += tot;
  }
  if (t == 0) rowstart[b * RS + NK2] = running;
  for (int i = t; i < NN; i += 256) {
    float sm = wtot[b * NK2 + i] + wtot[b * NK2 + NN + i];
    dinv[b * NN + i] = sm > 0.f ? rsqrtf(sm) : 0.f;
  }
}

// ---------------------------------------------------------------------------
// 4) fill CSR (no atomics), 2 edges/thread, dinv[src] pre-multiplied:
//    csr[pos] = {src, bits(w * dinv[src])}, nt-stores (csr lives in L3)
// ---------------------------------------------------------------------------
__global__ __launch_bounds__(256) void fill_kernel(
    const int* __restrict__ edges, const float* __restrict__ attr,
    const unsigned short* __restrict__ lrank, const unsigned short* __restrict__ hb,
    const int* __restrict__ rowstart, const float* __restrict__ dinv,
    int2* __restrict__ csr) {
  int b = blockIdx.y;
  int e0 = (blockIdx.x * 256 + threadIdx.x) * 2;
  int blk = e0 / EPB;   // both e0, e0+1 in same hist block (EPB even)
  int2 rr = *(const int2*)(edges + (size_t)b * 2 * EE + e0);
  int2 cc = *(const int2*)(edges + (size_t)b * 2 * EE + EE + e0);
  float2 ww = *(const float2*)(attr + (size_t)b * EE + e0);
  unsigned int lr2 = *(const unsigned int*)(lrank + (size_t)b * EE + e0);
  int k0 = ((rr.x >= HALFN) ? NN : 0) + cc.x;
  int k1 = ((rr.y >= HALFN) ? NN : 0) + cc.y;
  const unsigned short* hbrow = hb + ((size_t)(b * NHB + blk)) * NK2;
  int p0 = rowstart[b * RS + k0] + (int)hbrow[k0] + (int)(lr2 & 0xffffu);
  int p1 = rowstart[b * RS + k1] + (int)hbrow[k1] + (int)(lr2 >> 16);
  float w0 = ww.x * dinv[b * NN + rr.x];
  float w1 = ww.y * dinv[b * NN + rr.y];
  i32x2 v0; v0.x = rr.x; v0.y = __float_as_int(w0);
  i32x2 v1; v1.x = rr.y; v1.y = __float_as_int(w1);
  __builtin_nontemporal_store(v0, (i32x2*)(csr + (size_t)b * EE + p0));
  __builtin_nontemporal_store(v1, (i32x2*)(csr + (size_t)b * EE + p1));
}

// ---------------------------------------------------------------------------
// 5) register-tiled GEMM, 64 rows/block, thread = 4 rows x 8 cols.
//    fused==1: x = relu((p0+p1)*dinv[row] + xbias)  (prev layer's epilogue;
//    p reads REGULAR — each block re-reads its rows 4x, wants L2)
// ---------------------------------------------------------------------------
__global__ __launch_bounds__(256) void gemm_kernel(
    const float* __restrict__ xsrc, const float* __restrict__ p0,
    const float* __restrict__ p1, const float* __restrict__ dinv,
    const float* __restrict__ xbias, const float* __restrict__ W,
    float* __restrict__ out, int fused) {
  __shared__ float xs[32 * 68];
  __shared__ float ws[32 * 144];
  int b = blockIdx.y;
  int row0 = blockIdx.x * 64;
  int t = threadIdx.x;
  int rg = t >> 4, cg = t & 15;
  int fc = cg * 8 + ((cg >> 2) << 2);
  float acc[4][8];
#pragma unroll
  for (int r = 0; r < 4; ++r)
#pragma unroll
    for (int j = 0; j < 8; ++j) acc[r][j] = 0.f;
  size_t gbase = (size_t)b * NN * HH;

  for (int k0 = 0; k0 < HH; k0 += 32) {
#pragma unroll
    for (int i = 0; i < 2; ++i) {
      int idx = t + i * 256;          // 0..511
      int rl = idx >> 3, kq = idx & 7;
      int row = row0 + rl;
      float4 v = make_float4(0.f, 0.f, 0.f, 0.f);
      if (row < NN) {
        size_t o = gbase + (size_t)row * HH + k0 + kq * 4;
        if (fused) {
          float4 u0 = *(const float4*)(p0 + o);
          float4 u1 = *(const float4*)(p1 + o);
          float dn = dinv[b * NN + row];
          float4 bb = *(const float4*)(xbias + k0 + kq * 4);
          v.x = fmaxf((u0.x + u1.x) * dn + bb.x, 0.f);
          v.y = fmaxf((u0.y + u1.y) * dn + bb.y, 0.f);
          v.z = fmaxf((u0.z + u1.z) * dn + bb.z, 0.f);
          v.w = fmaxf((u0.w + u1.w) * dn + bb.w, 0.f);
        } else {
          v = *(const float4*)(xsrc + o);
        }
      }
      xs[(kq * 4 + 0) * 68 + rl] = v.x;
      xs[(kq * 4 + 1) * 68 + rl] = v.y;
      xs[(kq * 4 + 2) * 68 + rl] = v.z;
      xs[(kq * 4 + 3) * 68 + rl] = v.w;
    }
#pragma unroll
    for (int i = 0; i < 4; ++i) {
      int idx = t + i * 256;          // 0..1023
      int kk = idx >> 5, c = (idx & 31) * 4;
      float4 v = *(const float4*)(W + (size_t)(k0 + kk) * HH + c);
      int f = c + ((c >> 5) << 2);
      *(float4*)&ws[kk * 144 + f] = v;
    }
    __syncthreads();
#pragma unroll 4
    for (int k = 0; k < 32; ++k) {
      float4 xv = *(const float4*)&xs[k * 68 + rg * 4];
      float4 w0 = *(const float4*)&ws[k * 144 + fc];
      float4 w1 = *(const float4*)&ws[k * 144 + fc + 4];
      const float* xp = (const float*)&xv;
#pragma unroll
      for (int r = 0; r < 4; ++r) {
        acc[r][0] += xp[r] * w0.x; acc[r][1] += xp[r] * w0.y;
        acc[r][2] += xp[r] * w0.z; acc[r][3] += xp[r] * w0.w;
        acc[r][4] += xp[r] * w1.x; acc[r][5] += xp[r] * w1.y;
        acc[r][6] += xp[r] * w1.z; acc[r][7] += xp[r] * w1.w;
      }
    }
    __syncthreads();
  }
#pragma unroll
  for (int r = 0; r < 4; ++r) {
    int row = row0 + rg * 4 + r;
    if (row < NN) {
      float* og = out + gbase + (size_t)row * HH + cg * 8;
      *(float4*)og = make_float4(acc[r][0], acc[r][1], acc[r][2], acc[r][3]);
      *(float4*)(og + 4) = make_float4(acc[r][4], acc[r][5], acc[r][6], acc[r][7]);
    }
  }
}

// ---------------------------------------------------------------------------
// 6) aggregation, one launch per layer. Group g=bid&7 -> (b=g>>1, q=g&1),
//    gathering only xw src-half q (2.56 MB, XCD-L2-resident). csr via
//    nt-loads, partial outputs via nt-stores -> L2 holds ONLY the xw slice.
// ---------------------------------------------------------------------------
__global__ __launch_bounds__(256) void agg_kernel(
    const float* __restrict__ xw, const int2* __restrict__ csr,
    const int* __restrict__ rowstart,
    float* __restrict__ p0g, float* __restrict__ p1g) {
  int g = blockIdx.x & 7;
  int b = g >> 1;
  int q = g & 1;
  int chunk = blockIdx.x >> 3;        // 0..1249
  int half = (threadIdx.x >> 5) & 1;
  int n = chunk * 8 + (threadIdx.x >> 6) * 2 + half;
  int sl = threadIdx.x & 31;
  int key = q * NN + n;
  int s0 = rowstart[b * RS + key], s1 = rowstart[b * RS + key + 1];
  const float* xwg = xw + (size_t)b * NN * HH;
  const int2* c = csr + (size_t)b * EE;
  float4 a0 = make_float4(0.f, 0.f, 0.f, 0.f);
  float4 a1 = make_float4(0.f, 0.f, 0.f, 0.f);
  float4 a2 = make_float4(0.f, 0.f, 0.f, 0.f);
  float4 a3 = make_float4(0.f, 0.f, 0.f, 0.f);
  int i = s0;
  for (; i + 4 <= s1; i += 4) {
    i32x2 e0 = __builtin_nontemporal_load((const i32x2*)(c + i));
    i32x2 e1 = __builtin_nontemporal_load((const i32x2*)(c + i + 1));
    i32x2 e2 = __builtin_nontemporal_load((const i32x2*)(c + i + 2));
    i32x2 e3 = __builtin_nontemporal_load((const i32x2*)(c + i + 3));
    float w0 = __int_as_float(e0.y);
    float w1 = __int_as_float(e1.y);
    float w2 = __int_as_float(e2.y);
    float w3 = __int_as_float(e3.y);
    float4 v0 = *(const float4*)(xwg + (size_t)e0.x * HH + sl * 4);
    float4 v1 = *(const float4*)(xwg + (size_t)e1.x * HH + sl * 4);
    float4 v2 = *(const float4*)(xwg + (size_t)e2.x * HH + sl * 4);
    float4 v3 = *(const float4*)(xwg + (size_t)e3.x * HH + sl * 4);
    a0.x += w0 * v0.x; a0.y += w0 * v0.y; a0.z += w0 * v0.z; a0.w += w0 * v0.w;
    a1.x += w1 * v1.x; a1.y += w1 * v1.y; a1.z += w1 * v1.z; a1.w += w1 * v1.w;
    a2.x += w2 * v2.x; a2.y += w2 * v2.y; a2.z += w2 * v2.z; a2.w += w2 * v2.w;
    a3.x += w3 * v3.x; a3.y += w3 * v3.y; a3.z += w3 * v3.z; a3.w += w3 * v3.w;
  }
  for (; i < s1; ++i) {
    i32x2 e0 = __builtin_nontemporal_load((const i32x2*)(c + i));
    float w0 = __int_as_float(e0.y);
    float4 v0 = *(const float4*)(xwg + (size_t)e0.x * HH + sl * 4);
    a0.x += w0 * v0.x; a0.y += w0 * v0.y; a0.z += w0 * v0.z; a0.w += w0 * v0.w;
  }
  a0.x += a1.x + a2.x + a3.x;
  a0.y += a1.y + a2.y + a3.y;
  a0.z += a1.z + a2.z + a3.z;
  a0.w += a1.w + a2.w + a3.w;
  float* pq = (q == 0) ? p0g : p1g;
  __builtin_nontemporal_store(*(const f32x4*)&a0,
                              (f32x4*)(pq + ((size_t)b * NN + n) * HH + sl * 4));
}

// ---------------------------------------------------------------------------
// 7) readout: fused layer-3 epilogue + mean + Wl
// ---------------------------------------------------------------------------
__global__ __launch_bounds__(64) void init_out_kernel(float* out, const float* __restrict__ bl) {
  if (threadIdx.x < BB) out[threadIdx.x] = bl[0];
}

__global__ __launch_bounds__(256) void final_kernel(
    const float* __restrict__ p0g, const float* __restrict__ p1g,
    const float* __restrict__ dinv, const float* __restrict__ b3,
    const float* __restrict__ Wl, float* __restrict__ out) {
  int b = blockIdx.y;
  int t = threadIdx.x;
  int f = t & 127;
  int rr = t >> 7;
  float bf = b3[f];
  const float* dv = dinv + b * NN;
  float p = 0.f;
  for (int n = blockIdx.x * 2 + rr; n < NN; n += gridDim.x * 2) {
    size_t o = ((size_t)b * NN + n) * HH + f;
    p += fmaxf((p0g[o] + p1g[o]) * dv[n] + bf, 0.f);
  }
  __shared__ float s[256];
  s[t] = p;
  __syncthreads();
  float v = 0.f;
  if (t < 128) v = (s[t] + s[t + 128]) * Wl[f];
  __syncthreads();
  s[t] = v;
  __syncthreads();
  for (int o = 64; o > 0; o >>= 1) {
    if (t < o) s[t] += s[t + o];
    __syncthreads();
  }
  if (t == 0) atomicAdd(&out[b], s[0] * (1.0f / NN));
}

// ---------------------------------------------------------------------------
extern "C" void kernel_launch(void* const* d_in, const int* in_sizes, int n_in,
                              void* d_out, int out_size, void* d_ws, size_t ws_size,
                              hipStream_t stream) {
  const float* feat = (const float*)d_in[0];
  const int* edges = (const int*)d_in[1];
  const float* attr = (const float*)d_in[2];
  const float* W1 = (const float*)d_in[3];
  const float* b1 = (const float*)d_in[4];
  const float* W2 = (const float*)d_in[5];
  const float* b2 = (const float*)d_in[6];
  const float* W3 = (const float*)d_in[7];
  const float* b3 = (const float*)d_in[8];
  const float* Wl = (const float*)d_in[9];
  const float* bl = (const float*)d_in[10];
  float* out = (float*)d_out;

  char* ws = (char*)d_ws;
  size_t off = 0;
  auto alloc = [&](size_t bytes) {
    size_t o = off;
    off = (off + bytes + 255) & ~(size_t)255;
    return o;
  };
  int*   cnt      = (int*)  (ws + alloc((size_t)BB * NK2 * 4));        // 320 KB
  int*   rowstart = (int*)  (ws + alloc((size_t)BB * RS * 4));         // 320 KB
  float* wtot     = (float*)(ws + alloc((size_t)BB * NK2 * 4));        // 320 KB
  float* dinv     = (float*)(ws + alloc((size_t)BB * NN * 4));         // 160 KB
  int2*  csr      = (int2*) (ws + alloc((size_t)BB * EE * 8));         // 10.24 MB
  float* xw       = (float*)(ws + alloc((size_t)BB * NN * HH * 4));    // 20.48 MB
  float* p0       = (float*)(ws + alloc((size_t)BB * NN * HH * 4));    // 20.48 MB
  float* p1       = (float*)(ws + alloc((size_t)BB * NN * HH * 4));    // 20.48 MB
  // transient aliases (dead before gemm/agg touch xw/p0/p1):
  unsigned short* lrank = (unsigned short*)xw;  // 2.56 MB, live hist..fill
  unsigned short* hb    = (unsigned short*)p0;  // 10.24 MB, live hist..fill
  float*          wsp   = (float*)p1;           // 20.48 MB, live hist..colscan

  dim3 hgrid(NHB, BB);
  hist_kernel<<<hgrid, 256, 0, stream>>>(edges, attr, hb, wsp, lrank);
  colscan_kernel<<<dim3((NK2 + 255) / 256, BB), 256, 0, stream>>>(hb, wsp, cnt, wtot);
  scan_kernel<<<BB, 256, 0, stream>>>(cnt, wtot, rowstart, dinv);
  dim3 egrid2(EE / 512, BB);   // 2 edges/thread
  fill_kernel<<<egrid2, 256, 0, stream>>>(edges, attr, lrank, hb, rowstart, dinv, csr);

  dim3 ggrid((NN + 63) / 64, BB);
  int agrid = 8 * (NN / 8);   // 8 XCD-groups x 1250 chunks (8 nodes/block)

  // layer 1: xw = feat@W1 ; p0/p1 partials
  gemm_kernel<<<ggrid, 256, 0, stream>>>(feat, nullptr, nullptr, nullptr, nullptr, W1, xw, 0);
  agg_kernel<<<agrid, 256, 0, stream>>>(xw, csr, rowstart, p0, p1);
  // layer 2: xw = relu((p0+p1)*dn+b1)@W2 ; partials
  gemm_kernel<<<ggrid, 256, 0, stream>>>(nullptr, p0, p1, dinv, b1, W2, xw, 1);
  agg_kernel<<<agrid, 256, 0, stream>>>(xw, csr, rowstart, p0, p1);
  // layer 3
  gemm_kernel<<<ggrid, 256, 0, stream>>>(nullptr, p0, p1, dinv, b2, W3, xw, 1);
  agg_kernel<<<agrid, 256, 0, stream>>>(xw, csr, rowstart, p0, p1);

  init_out_kernel<<<1, 64, 0, stream>>>(out, bl);
  final_kernel<<<dim3(64, BB), 256, 0, stream>>>(p0, p1, dinv, b3, Wl, out);
}